// Round 2
// baseline (524.422 us; speedup 1.0000x reference)
//
#include <hip/hip_runtime.h>
#include <hip/hip_bf16.h>
#include <math.h>

// ---------- types / helpers ----------
typedef __attribute__((ext_vector_type(8))) short bf16x8;
typedef __attribute__((ext_vector_type(4))) float f32x4;
typedef __attribute__((ext_vector_type(4))) unsigned short u16x4;

static __device__ __forceinline__ float bf2f(unsigned short u) {
    union { unsigned int i; float f; } v; v.i = ((unsigned int)u) << 16; return v.f;
}
static __device__ __forceinline__ unsigned short f2bf(float f) {
    union { float f; unsigned int i; } v; v.f = f;
    unsigned int x = v.i;
    return (unsigned short)((x + 0x7fffu + ((x >> 16) & 1u)) >> 16); // RNE
}
static __device__ __forceinline__ float sigmoidf(float v) {
    return 1.0f / (1.0f + expf(-v));
}
// async global->LDS, 16B per lane. LDS dest MUST be wave-uniform base + lane*16.
static __device__ __forceinline__ void gload16(const unsigned short* g, unsigned short* l) {
    __builtin_amdgcn_global_load_lds(
        (const __attribute__((address_space(1))) unsigned int*)g,
        (__attribute__((address_space(3))) unsigned int*)l, 16, 0, 0);
}

// ---------- Kernel A (merged): blocks [0,1024) = grayscale patchify + DFT magnitude + gate
// ----------                    blocks [1024,4096) = W1/W2 fp32->bf16 transpose ----------
__global__ __launch_bounds__(256) void kprep(
    const float* __restrict__ x, const float* __restrict__ lf,
    const float* __restrict__ mf, const float* __restrict__ hf,
    const float* __restrict__ W1, const float* __restrict__ W2,
    float* __restrict__ pr_out, unsigned short* __restrict__ mag_bf,
    float* __restrict__ ppsum, float* __restrict__ ppsq,
    unsigned short* __restrict__ w1t, unsigned short* __restrict__ w2t)
{
    __shared__ float sX[32][36];
    __shared__ float sYr[32][36];
    __shared__ float sYi[32][36];
    __shared__ float tc[32], ts[32];
    __shared__ float red_s[4], red_q[4];

    const int t = threadIdx.x;
    const int bid = blockIdx.x;

    if (bid >= 1024) {
        // ----- weight convert + transpose path (independent of patch path) -----
        int id = bid - 1024;
        float (*tile)[33] = (float (*)[33])(&sX[0][0]);  // 32*33*4 = 4224 B fits in sX (4608 B)
        const float* W; unsigned short* WT; int K, N, k0, n0;
        if (id < 1536) {
            W = W1; WT = w1t; K = 1024; N = 1536;
            k0 = (id & 31) * 32; n0 = (id >> 5) * 32;
        } else {
            id -= 1536;
            W = W2; WT = w2t; K = 1536; N = 1024;
            k0 = (id % 48) * 32; n0 = (id / 48) * 32;
        }
        const int tx = t & 31, ty = t >> 5;
        #pragma unroll
        for (int i = 0; i < 4; i++) {
            int r = ty + i * 8;
            tile[r][tx] = W[(long long)(k0 + r) * N + n0 + tx];
        }
        __syncthreads();
        #pragma unroll
        for (int i = 0; i < 4; i++) {
            int r = ty + i * 8;
            WT[(long long)(n0 + r) * K + k0 + tx] = f2bf(tile[tx][r]);
        }
        return;
    }

    // ----- patch path -----
    const int p = bid;
    const int b = p >> 6, l = p & 63;
    const int gy = l >> 3, gx = l & 7;
    const int lane = t & 63, wave = t >> 6;

    if (t < 32) {
        float ang = (float)t * 0.19634954084936207f; // 2*pi/32
        tc[t] = cosf(ang);
        ts[t] = sinf(ang);
    }

    const int y  = t >> 3;
    const int xc = (t & 7) * 4;
    const int h  = gy * 32 + y;
    const int wbase = gx * 32 + xc;
    const long long idx0 = ((long long)(b * 3 + 0) * 256 + h) * 256 + wbase;
    const long long idx1 = ((long long)(b * 3 + 1) * 256 + h) * 256 + wbase;
    const long long idx2 = ((long long)(b * 3 + 2) * 256 + h) * 256 + wbase;
    float4 r4 = *(const float4*)(x + idx0);
    float4 g4 = *(const float4*)(x + idx1);
    float4 b4 = *(const float4*)(x + idx2);
    float4 gray;
    gray.x = 0.299f * r4.x + 0.587f * g4.x + 0.114f * b4.x;
    gray.y = 0.299f * r4.y + 0.587f * g4.y + 0.114f * b4.y;
    gray.z = 0.299f * r4.z + 0.587f * g4.z + 0.114f * b4.z;
    gray.w = 0.299f * r4.w + 0.587f * g4.w + 0.114f * b4.w;
    *(float4*)&sX[y][xc] = gray;
    *(float4*)(pr_out + p * 1024 + t * 4) = gray;

    float ls = gray.x + gray.y + gray.z + gray.w;
    float lq = gray.x * gray.x + gray.y * gray.y + gray.z * gray.z + gray.w * gray.w;
    #pragma unroll
    for (int off = 32; off > 0; off >>= 1) {
        ls += __shfl_down(ls, off, 64);
        lq += __shfl_down(lq, off, 64);
    }
    if (lane == 0) { red_s[wave] = ls; red_q[wave] = lq; }
    __syncthreads();
    if (t == 0) {
        ppsum[p] = red_s[0] + red_s[1] + red_s[2] + red_s[3];
        ppsq[p]  = red_q[0] + red_q[1] + red_q[2] + red_q[3];
    }

    // stage 1: Y = F * X
    {
        const int k  = t >> 3;
        const int c0 = (t & 7) * 4;
        float yr[4] = {0,0,0,0}, yi[4] = {0,0,0,0};
        for (int n = 0; n < 32; n++) {
            int wi = (k * n) & 31;
            float cw = tc[wi], sw = ts[wi];
            float4 xv = *(const float4*)&sX[n][c0];
            yr[0] += cw * xv.x; yi[0] -= sw * xv.x;
            yr[1] += cw * xv.y; yi[1] -= sw * xv.y;
            yr[2] += cw * xv.z; yi[2] -= sw * xv.z;
            yr[3] += cw * xv.w; yi[3] -= sw * xv.w;
        }
        *(float4*)&sYr[k][c0] = *(float4*)yr;
        *(float4*)&sYi[k][c0] = *(float4*)yi;
    }
    __syncthreads();

    // stage 2: Z = Y * F^T, |Z|/32 * gate
    {
        const int k  = t >> 3;
        const int m0 = (t & 7) * 4;
        float zr[4] = {0,0,0,0}, zi[4] = {0,0,0,0};
        for (int c = 0; c < 32; c++) {
            float yr = sYr[k][c];
            float yi = sYi[k][c];
            #pragma unroll
            for (int j = 0; j < 4; j++) {
                int wi = ((m0 + j) * c) & 31;
                float cw = tc[wi], sw = ts[wi];
                zr[j] += yr * cw + yi * sw;
                zi[j] += yi * cw - yr * sw;
            }
        }
        const float sl = sigmoidf(lf[0]);
        const float sm = sigmoidf(mf[0]);
        const float sh = sigmoidf(hf[0]);
        const float T1 = 480.5f / 9.0f;
        const float T2 = 4.0f * 480.5f / 9.0f;
        const float fk = (float)k - 15.5f;
        u16x4 outv;
        #pragma unroll
        for (int j = 0; j < 4; j++) {
            float fm = (float)(m0 + j) - 15.5f;
            float r2 = fk * fk + fm * fm;
            float g = (r2 <= T1) ? sl : ((r2 <= T2) ? sm : sh);
            float magv = sqrtf(zr[j] * zr[j] + zi[j] * zi[j]) * 0.03125f * g;
            outv[j] = f2bf(magv);
        }
        *(u16x4*)(mag_bf + p * 1024 + k * 32 + m0) = outv;
    }
}

// ---------- GEMM1: hidden = relu(mag @ W1 + b1); 64x32 tile, BK=64, dbuf, grid (16,48) ----------
__global__ __launch_bounds__(256) void kgemm1(
    const unsigned short* __restrict__ A, const unsigned short* __restrict__ BT,
    const float* __restrict__ bias, unsigned short* __restrict__ C)
{
    const int K = 1024, N = 1536;
    __shared__ unsigned short sA[2][64 * 64];
    __shared__ unsigned short sB[2][32 * 64];

    const int t = threadIdx.x;
    const int lane = t & 63, wave = t >> 6;
    const int wm = wave & 1, wn = wave >> 1;        // wn in [0,2): 16-col group
    const int m0 = blockIdx.x * 64, n0 = blockIdx.y * 32;

    // A staging: chunk u in [0,512): row r=u>>3, slot s=u&7 holds global chunk c=s^(r&7)
    const int u0 = t, u1 = t + 256;
    const int ar0 = u0 >> 3, ac0 = (u0 & 7) ^ (ar0 & 7);
    const int ar1 = u1 >> 3, ac1 = (u1 & 7) ^ (ar1 & 7);
    const unsigned short* agp0 = A  + (long long)(m0 + ar0) * K + ac0 * 8;
    const unsigned short* agp1 = A  + (long long)(m0 + ar1) * K + ac1 * 8;
    // B staging: chunk u in [0,256): row r=u>>3 in [0,32)
    const int br = t >> 3, bc = (t & 7) ^ (br & 7);
    const unsigned short* bgp = BT + (long long)(n0 + br) * K + bc * 8;

    // fragment addresses
    const int lr = lane & 15, quad = lane >> 4;
    const int ra0 = wm * 32 + lr, ra1 = ra0 + 16;
    const int rb0 = wn * 16 + lr;
    const int ea = ra0 & 7, eb = rb0 & 7;

    f32x4 acc0 = {0,0,0,0}, acc1 = {0,0,0,0};

    // prologue: stage first K-chunk into buf 0
    gload16(agp0, sA[0] + u0 * 8);
    gload16(agp1, sA[0] + u1 * 8);
    gload16(bgp,  sB[0] + t * 8);
    __syncthreads();

    int buf = 0;
    for (int kk = 0; kk < K; kk += 64) {
        const int nx = kk + 64;
        if (nx < K) {
            gload16(agp0 + nx, sA[buf ^ 1] + u0 * 8);
            gload16(agp1 + nx, sA[buf ^ 1] + u1 * 8);
            gload16(bgp  + nx, sB[buf ^ 1] + t * 8);
        }
        const unsigned short* cA = sA[buf];
        const unsigned short* cB = sB[buf];
        #pragma unroll
        for (int st = 0; st < 2; st++) {
            const int cq = st * 4 + quad;
            bf16x8 a0 = *(const bf16x8*)(cA + ra0 * 64 + ((cq ^ ea) << 3));
            bf16x8 a1 = *(const bf16x8*)(cA + ra1 * 64 + ((cq ^ ea) << 3));
            bf16x8 b0 = *(const bf16x8*)(cB + rb0 * 64 + ((cq ^ eb) << 3));
            acc0 = __builtin_amdgcn_mfma_f32_16x16x32_bf16(a0, b0, acc0, 0, 0, 0);
            acc1 = __builtin_amdgcn_mfma_f32_16x16x32_bf16(a1, b0, acc1, 0, 0, 0);
        }
        __syncthreads();
        buf ^= 1;
    }

    const int col0 = n0 + wn * 16 + lr;
    const float bias0 = bias[col0];
    const int row0b = m0 + wm * 32 + quad * 4;
    #pragma unroll
    for (int r = 0; r < 4; r++) {
        int row0 = row0b + r, row1 = row0 + 16;
        C[(long long)row0 * N + col0] = f2bf(fmaxf(acc0[r] + bias0, 0.0f));
        C[(long long)row1 * N + col0] = f2bf(fmaxf(acc1[r] + bias0, 0.0f));
    }
}

// ---------- GEMM2 fused: attn = sigmoid(hidden @ W2 + b2); row-dot with mag -> wpart ----------
// 64x32 tile, grid (16,32); wpart parts = 64 (16 cols each)
__global__ __launch_bounds__(256) void kgemm2d(
    const unsigned short* __restrict__ A, const unsigned short* __restrict__ BT,
    const float* __restrict__ bias, const unsigned short* __restrict__ mag,
    float* __restrict__ wpart)
{
    const int K = 1536;
    __shared__ unsigned short sA[2][64 * 64];
    __shared__ unsigned short sB[2][32 * 64];

    const int t = threadIdx.x;
    const int lane = t & 63, wave = t >> 6;
    const int wm = wave & 1, wn = wave >> 1;
    const int m0 = blockIdx.x * 64, n0 = blockIdx.y * 32;

    const int u0 = t, u1 = t + 256;
    const int ar0 = u0 >> 3, ac0 = (u0 & 7) ^ (ar0 & 7);
    const int ar1 = u1 >> 3, ac1 = (u1 & 7) ^ (ar1 & 7);
    const unsigned short* agp0 = A  + (long long)(m0 + ar0) * K + ac0 * 8;
    const unsigned short* agp1 = A  + (long long)(m0 + ar1) * K + ac1 * 8;
    const int br = t >> 3, bc = (t & 7) ^ (br & 7);
    const unsigned short* bgp = BT + (long long)(n0 + br) * K + bc * 8;

    const int lr = lane & 15, quad = lane >> 4;
    const int ra0 = wm * 32 + lr, ra1 = ra0 + 16;
    const int rb0 = wn * 16 + lr;
    const int ea = ra0 & 7, eb = rb0 & 7;

    f32x4 acc0 = {0,0,0,0}, acc1 = {0,0,0,0};

    gload16(agp0, sA[0] + u0 * 8);
    gload16(agp1, sA[0] + u1 * 8);
    gload16(bgp,  sB[0] + t * 8);
    __syncthreads();

    int buf = 0;
    for (int kk = 0; kk < K; kk += 64) {
        const int nx = kk + 64;
        if (nx < K) {
            gload16(agp0 + nx, sA[buf ^ 1] + u0 * 8);
            gload16(agp1 + nx, sA[buf ^ 1] + u1 * 8);
            gload16(bgp  + nx, sB[buf ^ 1] + t * 8);
        }
        const unsigned short* cA = sA[buf];
        const unsigned short* cB = sB[buf];
        #pragma unroll
        for (int st = 0; st < 2; st++) {
            const int cq = st * 4 + quad;
            bf16x8 a0 = *(const bf16x8*)(cA + ra0 * 64 + ((cq ^ ea) << 3));
            bf16x8 a1 = *(const bf16x8*)(cA + ra1 * 64 + ((cq ^ ea) << 3));
            bf16x8 b0 = *(const bf16x8*)(cB + rb0 * 64 + ((cq ^ eb) << 3));
            acc0 = __builtin_amdgcn_mfma_f32_16x16x32_bf16(a0, b0, acc0, 0, 0, 0);
            acc1 = __builtin_amdgcn_mfma_f32_16x16x32_bf16(a1, b0, acc1, 0, 0, 0);
        }
        __syncthreads();
        buf ^= 1;
    }

    const int col0 = n0 + wn * 16 + lr;
    const float bias0 = bias[col0];
    const int row0b = m0 + wm * 32 + quad * 4;

    float dsum0[4], dsum1[4];
    #pragma unroll
    for (int r = 0; r < 4; r++) {
        int row0 = row0b + r, row1 = row0 + 16;
        float v0 = sigmoidf(acc0[r] + bias0);
        float v1 = sigmoidf(acc1[r] + bias0);
        float m0v = bf2f(mag[(long long)row0 * 1024 + col0]);
        float m1v = bf2f(mag[(long long)row1 * 1024 + col0]);
        dsum0[r] = m0v * v0;
        dsum1[r] = m1v * v1;
    }
    #pragma unroll
    for (int r = 0; r < 4; r++) {
        #pragma unroll
        for (int mask = 8; mask > 0; mask >>= 1) {
            dsum0[r] += __shfl_xor(dsum0[r], mask, 64);
            dsum1[r] += __shfl_xor(dsum1[r], mask, 64);
        }
    }
    if (lr == 0) {
        const int cp = blockIdx.y * 2 + wn;   // [0,64)
        #pragma unroll
        for (int r = 0; r < 4; r++) {
            wpart[(row0b + r) * 64 + cp]      = dsum0[r];
            wpart[(row0b + 16 + r) * 64 + cp] = dsum1[r];
        }
    }
}

// ---------- finalize: per-patch scale + BN-collapsed affine constants ----------
__global__ __launch_bounds__(1024) void kfin(
    const float* __restrict__ wpart, const float* __restrict__ ppsum,
    const float* __restrict__ ppsq, const float* __restrict__ w_proj,
    const float* __restrict__ gamma, const float* __restrict__ beta,
    float* __restrict__ scales, float* __restrict__ der)
{
    __shared__ float rs[16], rq[16];
    const int p = threadIdx.x;
    const int lane = p & 63, wave = p >> 6;

    const float4* wp4 = (const float4*)(wpart + p * 64);
    float w = 0.0f;
    #pragma unroll
    for (int j = 0; j < 16; j++) {
        float4 v = wp4[j];
        w += v.x + v.y + v.z + v.w;
    }
    float scale = 1.0f + w * (1.0f / 1024.0f);
    scales[p] = scale;

    float s = scale * ppsum[p];
    float q = scale * scale * ppsq[p];
    #pragma unroll
    for (int off = 32; off > 0; off >>= 1) {
        s += __shfl_down(s, off, 64);
        q += __shfl_down(q, off, 64);
    }
    if (lane == 0) { rs[wave] = s; rq[wave] = q; }
    __syncthreads();
    if (p < 64) {
        float S = (p < 16) ? rs[p] : 0.0f;
        float Q = (p < 16) ? rq[p] : 0.0f;
        #pragma unroll
        for (int off = 8; off > 0; off >>= 1) {
            S += __shfl_down(S, off, 64);
            Q += __shfl_down(Q, off, 64);
        }
        S = __shfl(S, 0, 64);
        Q = __shfl(Q, 0, 64);
        const float invN = 1.0f / 1048576.0f;
        float mu  = S * invN;
        float var = Q * invN - mu * mu;
        float wp = w_proj[p];
        float A = wp * gamma[p] / sqrtf(wp * wp * var + 1e-5f);
        der[p]      = A;
        der[64 + p] = beta[p] - A * mu;
    }
}

// ---------- output: broadcast to 64 channels, affine + relu; 64B per thread-iter ----------
__global__ __launch_bounds__(256) void kout(
    const float* __restrict__ pr, const float* __restrict__ scales,
    const float* __restrict__ der, float* __restrict__ out)
{
    const int total16 = 4194304;   // 16M float4 / 4
    for (int i = blockIdx.x * 256 + threadIdx.x; i < total16; i += gridDim.x * 256) {
        const int i4 = i << 2;
        const int w4 = i4 & 63;
        const int h = (i4 >> 6) & 255;
        const int plane = i4 >> 14;
        const int c = plane & 63;
        const int b = plane >> 6;
        const int p = (b << 6) + ((h >> 5) << 3) + (w4 >> 3);
        const int off4 = ((h & 31) << 3) + (w4 & 7);
        const float As = der[c] * scales[p];
        const float D2 = der[64 + c];
        const float4* src = (const float4*)pr + p * 256 + off4;
        #pragma unroll
        for (int j = 0; j < 4; j++) {
            float4 v = src[j];
            f32x4 o;
            o[0] = fmaxf(fmaf(As, v.x, D2), 0.0f);
            o[1] = fmaxf(fmaf(As, v.y, D2), 0.0f);
            o[2] = fmaxf(fmaf(As, v.z, D2), 0.0f);
            o[3] = fmaxf(fmaf(As, v.w, D2), 0.0f);
            __builtin_nontemporal_store(o, (f32x4*)out + i4 + j);
        }
    }
}

// ---------- launch ----------
extern "C" void kernel_launch(void* const* d_in, const int* in_sizes, int n_in,
                              void* d_out, int out_size, void* d_ws, size_t ws_size,
                              hipStream_t stream)
{
    const float* x      = (const float*)d_in[0];
    const float* W1     = (const float*)d_in[1];
    const float* b1     = (const float*)d_in[2];
    const float* W2     = (const float*)d_in[3];
    const float* b2     = (const float*)d_in[4];
    const float* w_proj = (const float*)d_in[5];
    const float* gamma  = (const float*)d_in[6];
    const float* beta   = (const float*)d_in[7];
    const float* lf     = (const float*)d_in[8];
    const float* mf     = (const float*)d_in[9];
    const float* hf     = (const float*)d_in[10];

    char* ws = (char*)d_ws;
    float* pr                 = (float*)(ws);                      // 4 MB
    unsigned short* mag_bf    = (unsigned short*)(ws + (4u<<20));  // 2 MB
    unsigned short* hidden_bf = (unsigned short*)(ws + (6u<<20));  // 3 MB
    unsigned short* w1t       = (unsigned short*)(ws + (10u<<20)); // 3 MB
    unsigned short* w2t       = (unsigned short*)(ws + (13u<<20)); // 3 MB
    float* wpart              = (float*)(ws + (16u<<20));          // 256 KB
    float* ppsum              = (float*)(ws + (17u<<20));          // 4 KB
    float* ppsq               = (float*)(ws + (17u<<20) + 4096);   // 4 KB
    float* scales             = (float*)(ws + (17u<<20) + 8192);   // 4 KB
    float* der                = (float*)(ws + (17u<<20) + 12288);  // 512 B

    kprep<<<4096, 256, 0, stream>>>(x, lf, mf, hf, W1, W2, pr, mag_bf, ppsum, ppsq, w1t, w2t);
    kgemm1<<<dim3(16, 48), 256, 0, stream>>>(mag_bf, w1t, b1, hidden_bf);
    kgemm2d<<<dim3(16, 32), 256, 0, stream>>>(hidden_bf, w2t, b2, mag_bf, wpart);
    kfin<<<1, 1024, 0, stream>>>(wpart, ppsum, ppsq, w_proj, gamma, beta, scales, der);
    kout<<<2048, 256, 0, stream>>>(pr, scales, der, (float*)d_out);
}

// Round 3
// 343.691 us; speedup vs baseline: 1.5259x; 1.5259x over previous
//
#include <hip/hip_runtime.h>
#include <hip/hip_bf16.h>
#include <math.h>

// ---------- types / helpers ----------
typedef __attribute__((ext_vector_type(8))) short bf16x8;
typedef __attribute__((ext_vector_type(4))) float f32x4;
typedef __attribute__((ext_vector_type(4))) unsigned short u16x4;

static __device__ __forceinline__ float bf2f(unsigned short u) {
    union { unsigned int i; float f; } v; v.i = ((unsigned int)u) << 16; return v.f;
}
static __device__ __forceinline__ unsigned short f2bf(float f) {
    union { float f; unsigned int i; } v; v.f = f;
    unsigned int x = v.i;
    return (unsigned short)((x + 0x7fffu + ((x >> 16) & 1u)) >> 16); // RNE
}
static __device__ __forceinline__ float sigmoidf(float v) {
    return 1.0f / (1.0f + expf(-v));
}
// async global->LDS, 16B per lane. LDS dest MUST be wave-uniform base + lane*16.
static __device__ __forceinline__ void gload16(const unsigned short* g, unsigned short* l) {
    __builtin_amdgcn_global_load_lds(
        (const __attribute__((address_space(1))) unsigned int*)g,
        (__attribute__((address_space(3))) unsigned int*)l, 16, 0, 0);
}

// ---------- Kernel A (merged): blocks [0,1024) = grayscale patchify + DFT magnitude + gate
// ----------                    blocks [1024,4096) = W1/W2 fp32->bf16 transpose ----------
__global__ __launch_bounds__(256) void kprep(
    const float* __restrict__ x, const float* __restrict__ lf,
    const float* __restrict__ mf, const float* __restrict__ hf,
    const float* __restrict__ W1, const float* __restrict__ W2,
    float* __restrict__ pr_out, unsigned short* __restrict__ mag_bf,
    float* __restrict__ ppsum, float* __restrict__ ppsq,
    unsigned short* __restrict__ w1t, unsigned short* __restrict__ w2t,
    float* __restrict__ wsum, int* __restrict__ cnt)
{
    __shared__ float sX[32][36];
    __shared__ float sYr[32][36];
    __shared__ float sYi[32][36];
    __shared__ float tc[32], ts[32];
    __shared__ float red_s[4], red_q[4];

    const int t = threadIdx.x;
    const int bid = blockIdx.x;

    if (bid >= 1024) {
        // ----- weight convert + transpose path (independent of patch path) -----
        int id = bid - 1024;
        if (id == 0) {
            // zero the gemm2 accumulation buffer + completion counter (re-poisoned每 iteration)
            #pragma unroll
            for (int j = 0; j < 4; j++) wsum[j * 256 + t] = 0.0f;
            if (t == 0) *cnt = 0;
        }
        float (*tile)[33] = (float (*)[33])(&sX[0][0]);  // 32*33*4 = 4224 B fits in sX
        const float* W; unsigned short* WT; int K, N, k0, n0;
        if (id < 1536) {
            W = W1; WT = w1t; K = 1024; N = 1536;
            k0 = (id & 31) * 32; n0 = (id >> 5) * 32;
        } else {
            id -= 1536;
            W = W2; WT = w2t; K = 1536; N = 1024;
            k0 = (id % 48) * 32; n0 = (id / 48) * 32;
        }
        const int tx = t & 31, ty = t >> 5;
        #pragma unroll
        for (int i = 0; i < 4; i++) {
            int r = ty + i * 8;
            tile[r][tx] = W[(long long)(k0 + r) * N + n0 + tx];
        }
        __syncthreads();
        #pragma unroll
        for (int i = 0; i < 4; i++) {
            int r = ty + i * 8;
            WT[(long long)(n0 + r) * K + k0 + tx] = f2bf(tile[tx][r]);
        }
        return;
    }

    // ----- patch path -----
    const int p = bid;
    const int b = p >> 6, l = p & 63;
    const int gy = l >> 3, gx = l & 7;
    const int lane = t & 63, wave = t >> 6;

    if (t < 32) {
        float ang = (float)t * 0.19634954084936207f; // 2*pi/32
        tc[t] = cosf(ang);
        ts[t] = sinf(ang);
    }

    const int y  = t >> 3;
    const int xc = (t & 7) * 4;
    const int h  = gy * 32 + y;
    const int wbase = gx * 32 + xc;
    const long long idx0 = ((long long)(b * 3 + 0) * 256 + h) * 256 + wbase;
    const long long idx1 = ((long long)(b * 3 + 1) * 256 + h) * 256 + wbase;
    const long long idx2 = ((long long)(b * 3 + 2) * 256 + h) * 256 + wbase;
    float4 r4 = *(const float4*)(x + idx0);
    float4 g4 = *(const float4*)(x + idx1);
    float4 b4 = *(const float4*)(x + idx2);
    float4 gray;
    gray.x = 0.299f * r4.x + 0.587f * g4.x + 0.114f * b4.x;
    gray.y = 0.299f * r4.y + 0.587f * g4.y + 0.114f * b4.y;
    gray.z = 0.299f * r4.z + 0.587f * g4.z + 0.114f * b4.z;
    gray.w = 0.299f * r4.w + 0.587f * g4.w + 0.114f * b4.w;
    *(float4*)&sX[y][xc] = gray;
    *(float4*)(pr_out + p * 1024 + t * 4) = gray;

    float ls = gray.x + gray.y + gray.z + gray.w;
    float lq = gray.x * gray.x + gray.y * gray.y + gray.z * gray.z + gray.w * gray.w;
    #pragma unroll
    for (int off = 32; off > 0; off >>= 1) {
        ls += __shfl_down(ls, off, 64);
        lq += __shfl_down(lq, off, 64);
    }
    if (lane == 0) { red_s[wave] = ls; red_q[wave] = lq; }
    __syncthreads();
    if (t == 0) {
        ppsum[p] = red_s[0] + red_s[1] + red_s[2] + red_s[3];
        ppsq[p]  = red_q[0] + red_q[1] + red_q[2] + red_q[3];
    }

    // stage 1: Y = F * X
    {
        const int k  = t >> 3;
        const int c0 = (t & 7) * 4;
        float yr[4] = {0,0,0,0}, yi[4] = {0,0,0,0};
        for (int n = 0; n < 32; n++) {
            int wi = (k * n) & 31;
            float cw = tc[wi], sw = ts[wi];
            float4 xv = *(const float4*)&sX[n][c0];
            yr[0] += cw * xv.x; yi[0] -= sw * xv.x;
            yr[1] += cw * xv.y; yi[1] -= sw * xv.y;
            yr[2] += cw * xv.z; yi[2] -= sw * xv.z;
            yr[3] += cw * xv.w; yi[3] -= sw * xv.w;
        }
        *(float4*)&sYr[k][c0] = *(float4*)yr;
        *(float4*)&sYi[k][c0] = *(float4*)yi;
    }
    __syncthreads();

    // stage 2: Z = Y * F^T, |Z|/32 * gate
    {
        const int k  = t >> 3;
        const int m0 = (t & 7) * 4;
        float zr[4] = {0,0,0,0}, zi[4] = {0,0,0,0};
        for (int c = 0; c < 32; c++) {
            float yr = sYr[k][c];
            float yi = sYi[k][c];
            #pragma unroll
            for (int j = 0; j < 4; j++) {
                int wi = ((m0 + j) * c) & 31;
                float cw = tc[wi], sw = ts[wi];
                zr[j] += yr * cw + yi * sw;
                zi[j] += yi * cw - yr * sw;
            }
        }
        const float sl = sigmoidf(lf[0]);
        const float sm = sigmoidf(mf[0]);
        const float sh = sigmoidf(hf[0]);
        const float T1 = 480.5f / 9.0f;
        const float T2 = 4.0f * 480.5f / 9.0f;
        const float fk = (float)k - 15.5f;
        u16x4 outv;
        #pragma unroll
        for (int j = 0; j < 4; j++) {
            float fm = (float)(m0 + j) - 15.5f;
            float r2 = fk * fk + fm * fm;
            float g = (r2 <= T1) ? sl : ((r2 <= T2) ? sm : sh);
            float magv = sqrtf(zr[j] * zr[j] + zi[j] * zi[j]) * 0.03125f * g;
            outv[j] = f2bf(magv);
        }
        *(u16x4*)(mag_bf + p * 1024 + k * 32 + m0) = outv;
    }
}

// ---------- GEMM1: hidden = relu(mag @ W1 + b1); 64x32 tile, BK=128, dbuf, grid (16,48) ----------
__global__ __launch_bounds__(256) void kgemm1(
    const unsigned short* __restrict__ A, const unsigned short* __restrict__ BT,
    const float* __restrict__ bias, unsigned short* __restrict__ C)
{
    const int K = 1024, N = 1536;
    __shared__ unsigned short sA[2][64 * 128];
    __shared__ unsigned short sB[2][32 * 128];

    const int t = threadIdx.x;
    const int lane = t & 63, wave = t >> 6;
    const int wm = wave & 1, wn = wave >> 1;
    const int m0 = blockIdx.x * 64, n0 = blockIdx.y * 32;

    // staging: 16 slots of 8 bf16 per row; slot s at row r holds global chunk c = s^(r&7)
    const unsigned short* agp[4]; int aoff[4];
    #pragma unroll
    for (int j = 0; j < 4; j++) {
        int u = j * 256 + t, r = u >> 4, s = u & 15, c = s ^ (r & 7);
        agp[j] = A + (long long)(m0 + r) * K + c * 8;
        aoff[j] = u * 8;
    }
    const unsigned short* bgp[2]; int boff[2];
    #pragma unroll
    for (int j = 0; j < 2; j++) {
        int u = j * 256 + t, r = u >> 4, s = u & 15, c = s ^ (r & 7);
        bgp[j] = BT + (long long)(n0 + r) * K + c * 8;
        boff[j] = u * 8;
    }

    const int lr = lane & 15, quad = lane >> 4;
    const int ra0 = wm * 32 + lr, ra1 = ra0 + 16;
    const int rb0 = wn * 16 + lr;
    const int ea = ra0 & 7, eb = rb0 & 7;

    f32x4 acc0 = {0,0,0,0}, acc1 = {0,0,0,0};

    #pragma unroll
    for (int j = 0; j < 4; j++) gload16(agp[j], sA[0] + aoff[j]);
    #pragma unroll
    for (int j = 0; j < 2; j++) gload16(bgp[j], sB[0] + boff[j]);
    __syncthreads();

    int buf = 0;
    for (int kk = 0; kk < K; kk += 128) {
        const int nx = kk + 128;
        if (nx < K) {
            #pragma unroll
            for (int j = 0; j < 4; j++) gload16(agp[j] + nx, sA[buf ^ 1] + aoff[j]);
            #pragma unroll
            for (int j = 0; j < 2; j++) gload16(bgp[j] + nx, sB[buf ^ 1] + boff[j]);
        }
        const unsigned short* cA = sA[buf];
        const unsigned short* cB = sB[buf];
        #pragma unroll
        for (int st = 0; st < 4; st++) {
            const int cq = st * 4 + quad;
            bf16x8 a0 = *(const bf16x8*)(cA + ra0 * 128 + ((cq ^ ea) << 3));
            bf16x8 a1 = *(const bf16x8*)(cA + ra1 * 128 + ((cq ^ ea) << 3));
            bf16x8 b0 = *(const bf16x8*)(cB + rb0 * 128 + ((cq ^ eb) << 3));
            acc0 = __builtin_amdgcn_mfma_f32_16x16x32_bf16(a0, b0, acc0, 0, 0, 0);
            acc1 = __builtin_amdgcn_mfma_f32_16x16x32_bf16(a1, b0, acc1, 0, 0, 0);
        }
        __syncthreads();
        buf ^= 1;
    }

    const int col0 = n0 + wn * 16 + lr;
    const float bias0 = bias[col0];
    const int row0b = m0 + wm * 32 + quad * 4;
    #pragma unroll
    for (int r = 0; r < 4; r++) {
        int row0 = row0b + r, row1 = row0 + 16;
        C[(long long)row0 * N + col0] = f2bf(fmaxf(acc0[r] + bias0, 0.0f));
        C[(long long)row1 * N + col0] = f2bf(fmaxf(acc1[r] + bias0, 0.0f));
    }
}

// ---------- GEMM2 fused: attn = sigmoid(hidden @ W2 + b2); row-dot with mag -> atomic wsum;
// ---------- last block finalizes BN constants (replaces kfin) ----------
__global__ __launch_bounds__(256) void kgemm2d(
    const unsigned short* __restrict__ A, const unsigned short* __restrict__ BT,
    const float* __restrict__ bias, const unsigned short* __restrict__ mag,
    float* __restrict__ wsum, int* __restrict__ cnt,
    const float* __restrict__ ppsum, const float* __restrict__ ppsq,
    const float* __restrict__ w_proj, const float* __restrict__ gamma,
    const float* __restrict__ beta,
    float* __restrict__ scales, float* __restrict__ der)
{
    const int K = 1536;
    __shared__ unsigned short sA[2][64 * 128];
    __shared__ unsigned short sB[2][32 * 128];
    __shared__ float rsf[4], rqf[4];
    __shared__ int lastFlag;

    const int t = threadIdx.x;
    const int lane = t & 63, wave = t >> 6;
    const int wm = wave & 1, wn = wave >> 1;
    const int m0 = blockIdx.x * 64, n0 = blockIdx.y * 32;

    const unsigned short* agp[4]; int aoff[4];
    #pragma unroll
    for (int j = 0; j < 4; j++) {
        int u = j * 256 + t, r = u >> 4, s = u & 15, c = s ^ (r & 7);
        agp[j] = A + (long long)(m0 + r) * K + c * 8;
        aoff[j] = u * 8;
    }
    const unsigned short* bgp[2]; int boff[2];
    #pragma unroll
    for (int j = 0; j < 2; j++) {
        int u = j * 256 + t, r = u >> 4, s = u & 15, c = s ^ (r & 7);
        bgp[j] = BT + (long long)(n0 + r) * K + c * 8;
        boff[j] = u * 8;
    }

    const int lr = lane & 15, quad = lane >> 4;
    const int ra0 = wm * 32 + lr, ra1 = ra0 + 16;
    const int rb0 = wn * 16 + lr;
    const int ea = ra0 & 7, eb = rb0 & 7;

    f32x4 acc0 = {0,0,0,0}, acc1 = {0,0,0,0};

    #pragma unroll
    for (int j = 0; j < 4; j++) gload16(agp[j], sA[0] + aoff[j]);
    #pragma unroll
    for (int j = 0; j < 2; j++) gload16(bgp[j], sB[0] + boff[j]);
    __syncthreads();

    int buf = 0;
    for (int kk = 0; kk < K; kk += 128) {
        const int nx = kk + 128;
        if (nx < K) {
            #pragma unroll
            for (int j = 0; j < 4; j++) gload16(agp[j] + nx, sA[buf ^ 1] + aoff[j]);
            #pragma unroll
            for (int j = 0; j < 2; j++) gload16(bgp[j] + nx, sB[buf ^ 1] + boff[j]);
        }
        const unsigned short* cA = sA[buf];
        const unsigned short* cB = sB[buf];
        #pragma unroll
        for (int st = 0; st < 4; st++) {
            const int cq = st * 4 + quad;
            bf16x8 a0 = *(const bf16x8*)(cA + ra0 * 128 + ((cq ^ ea) << 3));
            bf16x8 a1 = *(const bf16x8*)(cA + ra1 * 128 + ((cq ^ ea) << 3));
            bf16x8 b0 = *(const bf16x8*)(cB + rb0 * 128 + ((cq ^ eb) << 3));
            acc0 = __builtin_amdgcn_mfma_f32_16x16x32_bf16(a0, b0, acc0, 0, 0, 0);
            acc1 = __builtin_amdgcn_mfma_f32_16x16x32_bf16(a1, b0, acc1, 0, 0, 0);
        }
        __syncthreads();
        buf ^= 1;
    }

    const int col0 = n0 + wn * 16 + lr;
    const float bias0 = bias[col0];
    const int row0b = m0 + wm * 32 + quad * 4;

    float dsum0[4], dsum1[4];
    #pragma unroll
    for (int r = 0; r < 4; r++) {
        int row0 = row0b + r, row1 = row0 + 16;
        float v0 = sigmoidf(acc0[r] + bias0);
        float v1 = sigmoidf(acc1[r] + bias0);
        float m0v = bf2f(mag[(long long)row0 * 1024 + col0]);
        float m1v = bf2f(mag[(long long)row1 * 1024 + col0]);
        dsum0[r] = m0v * v0;
        dsum1[r] = m1v * v1;
    }
    #pragma unroll
    for (int r = 0; r < 4; r++) {
        #pragma unroll
        for (int mask = 8; mask > 0; mask >>= 1) {
            dsum0[r] += __shfl_xor(dsum0[r], mask, 64);
            dsum1[r] += __shfl_xor(dsum1[r], mask, 64);
        }
    }
    if (lr == 0) {
        #pragma unroll
        for (int r = 0; r < 4; r++) {
            atomicAdd(&wsum[row0b + r],      dsum0[r]);
            atomicAdd(&wsum[row0b + 16 + r], dsum1[r]);
        }
    }

    // ---- completion handshake: last block computes BN constants ----
    __syncthreads();   // per-wave vmcnt(0) drain => this block's atomics complete
    if (t == 0) {
        __threadfence();
        int old = atomicAdd(cnt, 1);
        lastFlag = (old == (int)(gridDim.x * gridDim.y) - 1);
    }
    __syncthreads();
    if (!lastFlag) return;

    float s = 0.0f, q = 0.0f;
    #pragma unroll
    for (int j = 0; j < 4; j++) {
        int p = j * 256 + t;
        float wv = __hip_atomic_load(&wsum[p], __ATOMIC_RELAXED, __HIP_MEMORY_SCOPE_AGENT);
        float scale = 1.0f + wv * (1.0f / 1024.0f);
        scales[p] = scale;
        s += scale * ppsum[p];
        q += scale * scale * ppsq[p];
    }
    #pragma unroll
    for (int off = 32; off > 0; off >>= 1) {
        s += __shfl_down(s, off, 64);
        q += __shfl_down(q, off, 64);
    }
    if (lane == 0) { rsf[wave] = s; rqf[wave] = q; }
    __syncthreads();
    if (t < 64) {
        float S = rsf[0] + rsf[1] + rsf[2] + rsf[3];
        float Q = rqf[0] + rqf[1] + rqf[2] + rqf[3];
        const float invN = 1.0f / 1048576.0f;
        float mu  = S * invN;
        float var = Q * invN - mu * mu;
        float wp = w_proj[t];
        float Ac = wp * gamma[t] / sqrtf(wp * wp * var + 1e-5f);
        der[t]      = Ac;
        der[64 + t] = beta[t] - Ac * mu;
    }
}

// ---------- output: broadcast to 64 channels, affine + relu (grid-stride, NT stores) ----------
__global__ __launch_bounds__(256) void kout(
    const float* __restrict__ pr, const float* __restrict__ scales,
    const float* __restrict__ der, float* __restrict__ out)
{
    const int total4 = 16777216;
    for (int i4 = blockIdx.x * 256 + threadIdx.x; i4 < total4; i4 += gridDim.x * 256) {
        const int w4 = i4 & 63;
        const int h = (i4 >> 6) & 255;
        const int plane = i4 >> 14;
        const int c = plane & 63;
        const int b = plane >> 6;
        const int p = (b << 6) + ((h >> 5) << 3) + (w4 >> 3);
        const int off4 = ((h & 31) << 3) + (w4 & 7);
        const float As = der[c] * scales[p];
        const float D2 = der[64 + c];
        float4 v = ((const float4*)pr)[p * 256 + off4];
        f32x4 o;
        o[0] = fmaxf(fmaf(As, v.x, D2), 0.0f);
        o[1] = fmaxf(fmaf(As, v.y, D2), 0.0f);
        o[2] = fmaxf(fmaf(As, v.z, D2), 0.0f);
        o[3] = fmaxf(fmaf(As, v.w, D2), 0.0f);
        __builtin_nontemporal_store(o, (f32x4*)out + i4);
    }
}

// ---------- launch ----------
extern "C" void kernel_launch(void* const* d_in, const int* in_sizes, int n_in,
                              void* d_out, int out_size, void* d_ws, size_t ws_size,
                              hipStream_t stream)
{
    const float* x      = (const float*)d_in[0];
    const float* W1     = (const float*)d_in[1];
    const float* b1     = (const float*)d_in[2];
    const float* W2     = (const float*)d_in[3];
    const float* b2     = (const float*)d_in[4];
    const float* w_proj = (const float*)d_in[5];
    const float* gamma  = (const float*)d_in[6];
    const float* beta   = (const float*)d_in[7];
    const float* lf     = (const float*)d_in[8];
    const float* mf     = (const float*)d_in[9];
    const float* hf     = (const float*)d_in[10];

    char* ws = (char*)d_ws;
    float* pr                 = (float*)(ws);                      // 4 MB
    unsigned short* mag_bf    = (unsigned short*)(ws + (4u<<20));  // 2 MB
    unsigned short* hidden_bf = (unsigned short*)(ws + (6u<<20));  // 3 MB
    unsigned short* w1t       = (unsigned short*)(ws + (10u<<20)); // 3 MB
    unsigned short* w2t       = (unsigned short*)(ws + (13u<<20)); // 3 MB
    float* wsum               = (float*)(ws + (16u<<20));          // 4 KB
    int*   cnt                = (int*)(ws + (16u<<20) + 4096);     // 4 B
    float* ppsum              = (float*)(ws + (17u<<20));          // 4 KB
    float* ppsq               = (float*)(ws + (17u<<20) + 4096);   // 4 KB
    float* scales             = (float*)(ws + (17u<<20) + 8192);   // 4 KB
    float* der                = (float*)(ws + (17u<<20) + 12288);  // 512 B

    kprep<<<4096, 256, 0, stream>>>(x, lf, mf, hf, W1, W2, pr, mag_bf, ppsum, ppsq, w1t, w2t, wsum, cnt);
    kgemm1<<<dim3(16, 48), 256, 0, stream>>>(mag_bf, w1t, b1, hidden_bf);
    kgemm2d<<<dim3(16, 32), 256, 0, stream>>>(hidden_bf, w2t, b2, mag_bf, wsum, cnt,
                                              ppsum, ppsq, w_proj, gamma, beta, scales, der);
    kout<<<2048, 256, 0, stream>>>(pr, scales, der, (float*)d_out);
}